// Round 9
// baseline (791.517 us; speedup 1.0000x reference)
//
#include <hip/hip_runtime.h>
#include <math.h>

// Problem constants: B=4, T=2048, C=1024, NH=16, H=64
#define T_LEN 2048
#define C_DIM 1024
#define C3    3072
#define NHEAD 16
#define HDIM  64

typedef __attribute__((ext_vector_type(8))) __bf16 bf16x8;
typedef __attribute__((ext_vector_type(8))) unsigned short u16x8;
typedef __attribute__((ext_vector_type(4))) float f32x4;
typedef __attribute__((ext_vector_type(2))) unsigned int u32x2;
typedef unsigned short ushort_t;

#define QK_SCALE 0.180336878f   // 1/sqrt(64) * log2(e), folded into Q

#if defined(__has_builtin)
#if __has_builtin(__builtin_amdgcn_exp2f)
#define FAST_EXP2(x) __builtin_amdgcn_exp2f(x)
#endif
#if __has_builtin(__builtin_amdgcn_permlane32_swap) && __has_builtin(__builtin_amdgcn_permlane16_swap)
#define HAVE_PERMLANE_SWAP 1
#endif
#endif
#ifndef FAST_EXP2
#define FAST_EXP2(x) exp2f(x)
#endif

__device__ __forceinline__ ushort_t f2bf(float f) {
    unsigned int u = __float_as_uint(f);
    unsigned int r = (u + 0x7FFFu + ((u >> 16) & 1u)) >> 16;  // RNE
    return (ushort_t)r;
}

#define GLL16(g, l) __builtin_amdgcn_global_load_lds( \
    (const __attribute__((address_space(1))) void*)(g), \
    (__attribute__((address_space(3))) void*)(l), 16, 0, 0)

// ---------------------------------------------------------------------------
// Fused prep: x cast (blocks 0..8191), W_attn transpose (8192..8959),
// W_proj transpose (8960..9215).
// ---------------------------------------------------------------------------
__global__ __launch_bounds__(256) void prep_inputs(
    const float* __restrict__ x, ushort_t* __restrict__ xb,
    const float* __restrict__ W1, ushort_t* __restrict__ Wt1,
    const float* __restrict__ W2, ushort_t* __restrict__ Wt2)
{
    __shared__ float t[64][65];
    const int bx = blockIdx.x;
    if (bx < 8192) {
        const int i = bx * 256 + threadIdx.x;
        const float4 v = ((const float4*)x)[i];
        ushort4 o;
        o.x = f2bf(v.x); o.y = f2bf(v.y); o.z = f2bf(v.z); o.w = f2bf(v.w);
        ((ushort4*)xb)[i] = o;
        return;
    }
    const float* W; ushort_t* Wt; int N, n0, k0;
    if (bx < 8960) {
        const int tt = bx - 8192;
        W = W1; Wt = Wt1; N = C3;
        n0 = (tt % 48) * 64; k0 = (tt / 48) * 64;
    } else {
        const int tt = bx - 8960;
        W = W2; Wt = Wt2; N = C_DIM;
        n0 = (tt % 16) * 64; k0 = (tt / 16) * 64;
    }
    const int K = C_DIM;
    const int c = threadIdx.x & 63, r4 = threadIdx.x >> 6;
#pragma unroll
    for (int i = 0; i < 16; i++) {
        int r = i * 4 + r4;
        t[r][c] = W[(size_t)(k0 + r) * N + n0 + c];
    }
    __syncthreads();
#pragma unroll
    for (int i = 0; i < 16; i++) {
        int r = i * 4 + r4;
        Wt[(size_t)(n0 + r) * K + k0 + c] = f2bf(t[c][r]);
    }
}

// ---------------------------------------------------------------------------
// bf16 MFMA GEMM: 128x128 tile, BK=64, 256 threads, XOR-swizzled unpadded
// LDS staged via global_load_lds width=16. 1D grid + XCD row-clustering.
// ---------------------------------------------------------------------------
template <bool OUT_BF16, bool QSCALE>
__global__ __launch_bounds__(256, 3) void gemm_bt_mfma(
    const ushort_t* __restrict__ A, const ushort_t* __restrict__ Bt,
    const float* __restrict__ bias, void* __restrict__ Cv,
    int M, int N, int K)
{
    __shared__ ushort_t Alds[128 * 64];   // 16 KB
    __shared__ ushort_t Blds[128 * 64];   // 16 KB

    const int tid = threadIdx.x;
    const int bid = blockIdx.x;
    const int jj = bid >> 3;
    const int m0 = (((bid & 7) << 3) | (jj & 7)) * 128;   // row tile
    const int n0 = (jj >> 3) * 128;                       // col tile
    const int w = tid >> 6;
    const int ln = tid & 63;
    const int quad = ln >> 4;
    const int r16 = ln & 15;
    const int wr0 = (w & 1) * 64;
    const int wc0 = (w >> 1) * 64;

    f32x4 acc[4][4] = {};

    const int srow = tid >> 3;                       // 0..31 (row within round)
    const int csrc8 = ((tid & 7) ^ (srow & 7)) * 8;  // swizzled source elem ofs
    const int sw = r16 & 7;

    for (int k0 = 0; k0 < K; k0 += 64) {
#pragma unroll
        for (int rr = 0; rr < 4; rr++) {
            const ushort_t* ga = A + (size_t)(m0 + rr * 32 + srow) * K + k0 + csrc8;
            GLL16(ga, Alds + rr * 2048 + tid * 8);
            const ushort_t* gb = Bt + (size_t)(n0 + rr * 32 + srow) * K + k0 + csrc8;
            GLL16(gb, Blds + rr * 2048 + tid * 8);
        }
        __syncthreads();

#pragma unroll
        for (int s = 0; s < 2; s++) {
            const int cpos = ((4 * s + quad) ^ sw) * 8;
            bf16x8 af[4], bfr[4];
#pragma unroll
            for (int i = 0; i < 4; i++)
                af[i] = *(const bf16x8*)(Alds + (wr0 + i * 16 + r16) * 64 + cpos);
#pragma unroll
            for (int j = 0; j < 4; j++)
                bfr[j] = *(const bf16x8*)(Blds + (wc0 + j * 16 + r16) * 64 + cpos);
#pragma unroll
            for (int i = 0; i < 4; i++)
#pragma unroll
                for (int j = 0; j < 4; j++)
                    acc[i][j] = __builtin_amdgcn_mfma_f32_16x16x32_bf16(
                        af[i], bfr[j], acc[i][j], 0, 0, 0);
        }
        __syncthreads();
    }

    const float scl = (QSCALE && n0 < C_DIM) ? QK_SCALE : 1.0f;

#pragma unroll
    for (int j = 0; j < 4; j++) {
        const int col = n0 + wc0 + j * 16 + r16;
        const float bv = bias[col];
#pragma unroll
        for (int i = 0; i < 4; i++) {
            const int rowb = m0 + wr0 + i * 16 + quad * 4;
#pragma unroll
            for (int r = 0; r < 4; r++) {
                const float v = (acc[i][j][r] + bv) * scl;
                if (OUT_BF16)
                    ((ushort_t*)Cv)[(size_t)(rowb + r) * N + col] = f2bf(v);
                else
                    ((float*)Cv)[(size_t)(rowb + r) * N + col] = v;
            }
        }
    }
}

// ---------------------------------------------------------------------------
// V pre-transpose: qkv V-slice [b][t][2C + h*64 + d] -> vtg[bh][d][t]
// ---------------------------------------------------------------------------
__global__ __launch_bounds__(256) void transpose_v(
    const ushort_t* __restrict__ qkv, ushort_t* __restrict__ vtg)
{
    __shared__ ushort_t Ts[64][72];
    const int t0 = blockIdx.x * 64;
    const int bh = blockIdx.y;
    const int b = bh >> 4, h = bh & 15;
    const ushort_t* src = qkv + (size_t)b * T_LEN * C3 + 2 * C_DIM + h * HDIM;
    const int tid = threadIdx.x;
    {
        const int r = tid >> 2, cs = (tid & 3) * 16;
        *(u16x8*)(&Ts[r][cs])     = *(const u16x8*)(src + (size_t)(t0 + r) * C3 + cs);
        *(u16x8*)(&Ts[r][cs + 8]) = *(const u16x8*)(src + (size_t)(t0 + r) * C3 + cs + 8);
    }
    __syncthreads();
    {
        const int d = tid >> 2, ts0 = (tid & 3) * 16;
        ushort_t* dst = vtg + ((size_t)bh * HDIM + d) * T_LEN + t0 + ts0;
        u16x8 o0, o1;
#pragma unroll
        for (int j = 0; j < 8; j++) o0[j] = Ts[ts0 + j][d];
#pragma unroll
        for (int j = 0; j < 8; j++) o1[j] = Ts[ts0 + 8 + j][d];
        *(u16x8*)dst = o0;
        *(u16x8*)(dst + 8) = o1;
    }
}

// ---------------------------------------------------------------------------
// MFMA flash attention v11: v9 + depth-2 pipeline (T15).
// QK^T(kt+1) is computed INSIDE iteration kt, overlapping the serial
// softmax(kt)->PV(kt) chain with an independent MFMA stream. sA/sB persist
// across the barrier (plain named arrays, compile-time indexed).
// Buffers: Ks double (QK^T(kt+1) reads slot (kt+1)&1 staged at kt-1;
// stage_K(kt+2) targets slot kt&1, last read before the kt-1 barrier);
// Vs TRIPLE (PV(kt) reads slot kt%3 in the same iteration stage_V(kt+2)
// writes slot (kt+2)%3 -- distinct; rotation via 3 offset vars, no modulo).
// LDS = 16+24 = 40 KB -> exactly 4 blocks/CU retained. One barrier/iter,
// full-iteration prefetch cover, head-clustered XCD swizzle -- all v9.
// ---------------------------------------------------------------------------

__device__ __forceinline__ void mask_diag(f32x4 (&s)[4], int qloc, int quad)
{
#pragma unroll
    for (int mb = 0; mb < 4; mb++)
#pragma unroll
        for (int r = 0; r < 4; r++)
            if (mb * 16 + quad * 4 + r > qloc) s[mb][r] = -1e30f;
}

// exp2 -> per-lane partial sum -> pack bf16 (RTZ) -> cross-quad permlane
// exchange -> PV B-frags. No LDS.
__device__ __forceinline__ void softmax_exchange(
    f32x4 (&s)[4], float& lacc, bf16x8 (&bp)[2])
{
    unsigned int pk[4][2];
#pragma unroll
    for (int mb = 0; mb < 4; mb++) {
        const float p0 = FAST_EXP2(s[mb][0]);
        const float p1 = FAST_EXP2(s[mb][1]);
        const float p2 = FAST_EXP2(s[mb][2]);
        const float p3 = FAST_EXP2(s[mb][3]);
        lacc += (p0 + p1) + (p2 + p3);
        pk[mb][0] = __builtin_amdgcn_perm(__float_as_uint(p1), __float_as_uint(p0), 0x07060302u);
        pk[mb][1] = __builtin_amdgcn_perm(__float_as_uint(p3), __float_as_uint(p2), 0x07060302u);
    }
#pragma unroll
    for (int s2 = 0; s2 < 2; s2++) {
        uint4 t;
#pragma unroll
        for (int u = 0; u < 2; u++) {
            unsigned int A = pk[2 * s2][u], B = pk[2 * s2 + 1][u];
            unsigned int out1, out2;
#ifdef HAVE_PERMLANE_SWAP
            u32x2 r1 = __builtin_amdgcn_permlane32_swap(A, B, false, false);
            u32x2 r2 = __builtin_amdgcn_permlane16_swap(r1.x, r1.y, false, false);
            out1 = r2.x; out2 = r2.y;
#else
            asm volatile("s_nop 1\n\t"
                         "v_permlane32_swap_b32 %0, %1\n\t"
                         "s_nop 1\n\t"
                         "v_permlane16_swap_b32 %0, %1"
                         : "+v"(A), "+v"(B));
            out1 = A; out2 = B;
#endif
            if (u == 0) { t.x = out1; t.z = out2; }
            else        { t.y = out1; t.w = out2; }
        }
        bp[s2] = *(bf16x8*)&t;
    }
}

// Issue the 2 global_load_lds for K tile [k][d] of iteration kt_ into
// double-buffer half buf_ (0/1). No waits.
#define STAGE_K(kt_, buf_) do {                                               \
    const int _k0 = (kt_) * 64;                                               \
    const int _bo = (buf_) * 4096;                                            \
    _Pragma("unroll")                                                         \
    for (int rr = 0; rr < 2; rr++) {                                          \
        const ushort_t* gk = basek + (size_t)(_k0 + rr * 32 + srow) * C3 + csrc8; \
        GLL16(gk, Ks + _bo + rr * 2048 + tid * 8);                            \
    }                                                                         \
} while (0)

// Same for Vt tile [d][k]; vofs_ is an element offset (slot * 4096).
#define STAGE_V(kt_, vofs_) do {                                              \
    const int _k0 = (kt_) * 64;                                               \
    _Pragma("unroll")                                                         \
    for (int rr = 0; rr < 2; rr++) {                                          \
        const ushort_t* gv = vrow + (size_t)(rr * 32 + srow) * T_LEN + _k0 + csrc8; \
        GLL16(gv, Vs + (vofs_) + rr * 2048 + tid * 8);                        \
    }                                                                         \
} while (0)

__global__ __launch_bounds__(256, 4) void attn_flash_mfma5(
    const ushort_t* __restrict__ qkv, const ushort_t* __restrict__ vtg,
    ushort_t* __restrict__ y)
{
    __shared__ ushort_t Ks[2 * 64 * 64];  // 16 KB, double-buffered
    __shared__ ushort_t Vs[3 * 64 * 64];  // 24 KB, TRIPLE-buffered

    // ---- head-clustered XCD swizzle ----
    const int bid = blockIdx.x;            // 0..1023
    const int i = (bid >> 3) >> 3;         // pair index 0..15
    const int bh = (bid & 7) * 8 + ((bid >> 3) & 7);
    const int b = bh >> 4, h = bh & 15;
    const int qA0 = i * 64;
    const int qB0 = (31 - i) * 64;
    const int lastkt = 31 - i;             // >= 16 always

    const int tid = threadIdx.x;
    const int w = tid >> 6;
    const int ln = tid & 63;
    const int quad = ln >> 4;
    const int r16 = ln & 15;
    const int qloc = w * 16 + r16;
    const int sw = r16 & 7;

    const int srow = tid >> 3;                       // 0..31
    const int csrc8 = ((tid & 7) ^ (srow & 7)) * 8;  // swizzled source chunk
    const int cpos0 = (quad ^ sw) * 8;               // s=0 read pos; s=1: ^32

    const ushort_t* baseq = qkv + (size_t)b * T_LEN * C3 + h * HDIM;
    const ushort_t* basek = baseq + C_DIM;
    const ushort_t* vrow = vtg + (size_t)bh * HDIM * T_LEN;

    // ---- prologue: stage kt=0,1; Q frags straight from global ----
    STAGE_K(0, 0);
    STAGE_V(0, 0);
    STAGE_K(1, 1);
    STAGE_V(1, 4096);

    bf16x8 aqA[2], aqB[2];
#pragma unroll
    for (int s = 0; s < 2; s++) {
        aqA[s] = *(const bf16x8*)(baseq + (size_t)(qA0 + qloc) * C3 + s * 32 + quad * 8);
        aqB[s] = *(const bf16x8*)(baseq + (size_t)(qB0 + qloc) * C3 + s * 32 + quad * 8);
    }

    f32x4 oA[4] = {}, oB[4] = {};
    float lA = 0.0f, lB = 0.0f;

    __syncthreads();   // drains all prologue stages; Ks0/Ks1/Vs0/Vs1 ready

    // ---- QK^T(0) (kt=0 is always dual since i >= 0) ----
    f32x4 sA[4] = {}, sB[4] = {};
#pragma unroll
    for (int s = 0; s < 2; s++)
#pragma unroll
        for (int mb = 0; mb < 4; mb++) {
            const bf16x8 ak = *(const bf16x8*)(Ks + (mb * 16 + r16) * 64 + (cpos0 ^ (s * 32)));
            sA[mb] = __builtin_amdgcn_mfma_f32_16x16x32_bf16(ak, aqA[s], sA[mb], 0, 0, 0);
            sB[mb] = __builtin_amdgcn_mfma_f32_16x16x32_bf16(ak, aqB[s], sB[mb], 0, 0, 0);
        }

    // V slot offsets: v0 = slot of kt, v1 = kt+1, v2 = kt+2 (rotating)
    int v0 = 0, v1 = 4096, v2 = 8192;

    for (int kt = 0; kt <= lastkt; kt++) {
        // stage kt+2 (cover = this whole iteration; drained at the barrier)
        if (kt + 2 <= lastkt) {
            STAGE_K(kt + 2, kt & 1);   // (kt+2)&1 == kt&1
            STAGE_V(kt + 2, v2);
        }
        const int kbn = ((kt + 1) & 1) * 4096;

        if (kt <= i) {
            // ---- dual: softmax+PV for A and B, then QK^T(kt+1) ----
            if (kt == i) mask_diag(sA, qloc, quad);
            bf16x8 bpA[2], bpB[2];
            softmax_exchange(sA, lA, bpA);
            softmax_exchange(sB, lB, bpB);
#pragma unroll
            for (int s = 0; s < 2; s++)
#pragma unroll
                for (int mb = 0; mb < 4; mb++) {
                    const bf16x8 av = *(const bf16x8*)(Vs + v0 + (mb * 16 + r16) * 64 + (cpos0 ^ (s * 32)));
                    oA[mb] = __builtin_amdgcn_mfma_f32_16x16x32_bf16(av, bpA[s], oA[mb], 0, 0, 0);
                    oB[mb] = __builtin_amdgcn_mfma_f32_16x16x32_bf16(av, bpB[s], oB[mb], 0, 0, 0);
                }
            if (kt < lastkt) {
                const bool dualn = (kt + 1 <= i);
#pragma unroll
                for (int mb = 0; mb < 4; mb++) { sB[mb] = (f32x4){}; sA[mb] = (f32x4){}; }
#pragma unroll
                for (int s = 0; s < 2; s++)
#pragma unroll
                    for (int mb = 0; mb < 4; mb++) {
                        const bf16x8 ak = *(const bf16x8*)(Ks + kbn + (mb * 16 + r16) * 64 + (cpos0 ^ (s * 32)));
                        sB[mb] = __builtin_amdgcn_mfma_f32_16x16x32_bf16(ak, aqB[s], sB[mb], 0, 0, 0);
                        if (dualn)
                            sA[mb] = __builtin_amdgcn_mfma_f32_16x16x32_bf16(ak, aqA[s], sA[mb], 0, 0, 0);
                    }
            }
        } else {
            // ---- single: B only ----
            if (kt == lastkt) mask_diag(sB, qloc, quad);
            bf16x8 bpB[2];
            softmax_exchange(sB, lB, bpB);
#pragma unroll
            for (int s = 0; s < 2; s++)
#pragma unroll
                for (int mb = 0; mb < 4; mb++) {
                    const bf16x8 av = *(const bf16x8*)(Vs + v0 + (mb * 16 + r16) * 64 + (cpos0 ^ (s * 32)));
                    oB[mb] = __builtin_amdgcn_mfma_f32_16x16x32_bf16(av, bpB[s], oB[mb], 0, 0, 0);
                }
            if (kt < lastkt) {
#pragma unroll
                for (int mb = 0; mb < 4; mb++) sB[mb] = (f32x4){};
#pragma unroll
                for (int s = 0; s < 2; s++)
#pragma unroll
                    for (int mb = 0; mb < 4; mb++) {
                        const bf16x8 ak = *(const bf16x8*)(Ks + kbn + (mb * 16 + r16) * 64 + (cpos0 ^ (s * 32)));
                        sB[mb] = __builtin_amdgcn_mfma_f32_16x16x32_bf16(ak, aqB[s], sB[mb], 0, 0, 0);
                    }
            }
        }

        // rotate V slots: kt+1 becomes current
        const int vt = v0; v0 = v1; v1 = v2; v2 = vt;

        // Single barrier: implicit vmcnt(0) drains stage(kt+2) (covered by
        // this whole iteration); lgkmcnt(0) closes this iteration's reads of
        // the slots overwritten next iteration.
        __syncthreads();
    }

    // ---- epilogue: reduce l across the 4 lanes sharing each q, store ----
    lA += __shfl_xor(lA, 16); lA += __shfl_xor(lA, 32);
    lB += __shfl_xor(lB, 16); lB += __shfl_xor(lB, 32);
    {
        const float invA = 1.0f / lA;
        ushort_t* yp = y + ((size_t)(b * T_LEN + qA0 + qloc)) * C_DIM + h * HDIM;
#pragma unroll
        for (int mb = 0; mb < 4; mb++) {
            ushort4 o;
            o.x = f2bf(oA[mb][0] * invA);
            o.y = f2bf(oA[mb][1] * invA);
            o.z = f2bf(oA[mb][2] * invA);
            o.w = f2bf(oA[mb][3] * invA);
            *(ushort4*)(yp + mb * 16 + quad * 4) = o;
        }
    }
    {
        const float invB = 1.0f / lB;
        ushort_t* yp = y + ((size_t)(b * T_LEN + qB0 + qloc)) * C_DIM + h * HDIM;
#pragma unroll
        for (int mb = 0; mb < 4; mb++) {
            ushort4 o;
            o.x = f2bf(oB[mb][0] * invB);
            o.y = f2bf(oB[mb][1] * invB);
            o.z = f2bf(oB[mb][2] * invB);
            o.w = f2bf(oB[mb][3] * invB);
            *(ushort4*)(yp + mb * 16 + quad * 4) = o;
        }
    }
}

// ---------------------------------------------------------------------------
extern "C" void kernel_launch(void* const* d_in, const int* in_sizes, int n_in,
                              void* d_out, int out_size, void* d_ws, size_t ws_size,
                              hipStream_t stream)
{
    const float* x      = (const float*)d_in[0];
    const float* W_attn = (const float*)d_in[1];
    const float* b_attn = (const float*)d_in[2];
    const float* W_proj = (const float*)d_in[3];
    const float* b_proj = (const float*)d_in[4];
    float* out = (float*)d_out;

    const int M = 4 * T_LEN;  // 8192
    char* ws = (char*)d_ws;
    ushort_t* qkv = (ushort_t*)ws;
    ushort_t* xb  = (ushort_t*)(ws + 50331648);
    ushort_t* Wt1 = (ushort_t*)(ws + 67108864);
    ushort_t* yb  = (ushort_t*)(ws + 73400320);
    ushort_t* Wt2 = (ushort_t*)(ws + 90177536);
    ushort_t* vtg = (ushort_t*)(ws + 92274688);

    prep_inputs<<<9216, 256, 0, stream>>>(x, xb, W_attn, Wt1, W_proj, Wt2);

    // 1) qkv = x @ W_attn + b_attn (bf16; Q pre-scaled). 1D grid, XCD-clustered.
    gemm_bt_mfma<true, true><<<dim3((M / 128) * (C3 / 128)), 256, 0, stream>>>(
        xb, Wt1, b_attn, qkv, M, C3, C_DIM);

    transpose_v<<<dim3(T_LEN / 64, 4 * NHEAD), 256, 0, stream>>>(qkv, vtg);

    // 2) causal flash attention (v11, depth-2 pipelined) -> yb bf16
    attn_flash_mfma5<<<dim3(1024), 256, 0, stream>>>(qkv, vtg, yb);

    // 3) out = y @ W_proj + b_proj (f32 out). 1D grid, XCD-clustered.
    gemm_bt_mfma<false, false><<<dim3((M / 128) * (C_DIM / 128)), 256, 0, stream>>>(
        yb, Wt2, b_proj, out, M, C_DIM, C_DIM);
}

// Round 10
// 265.783 us; speedup vs baseline: 2.9781x; 2.9781x over previous
//
#include <hip/hip_runtime.h>
#include <math.h>

// Problem constants: B=4, T=2048, C=1024, NH=16, H=64
#define T_LEN 2048
#define C_DIM 1024
#define C3    3072
#define NHEAD 16
#define HDIM  64

typedef __attribute__((ext_vector_type(8))) __bf16 bf16x8;
typedef __attribute__((ext_vector_type(8))) unsigned short u16x8;
typedef __attribute__((ext_vector_type(4))) float f32x4;
typedef __attribute__((ext_vector_type(2))) unsigned int u32x2;
typedef unsigned short ushort_t;

#define QK_SCALE 0.180336878f   // 1/sqrt(64) * log2(e), folded into Q

#if defined(__has_builtin)
#if __has_builtin(__builtin_amdgcn_exp2f)
#define FAST_EXP2(x) __builtin_amdgcn_exp2f(x)
#endif
#if __has_builtin(__builtin_amdgcn_permlane32_swap) && __has_builtin(__builtin_amdgcn_permlane16_swap)
#define HAVE_PERMLANE_SWAP 1
#endif
#endif
#ifndef FAST_EXP2
#define FAST_EXP2(x) exp2f(x)
#endif

__device__ __forceinline__ ushort_t f2bf(float f) {
    unsigned int u = __float_as_uint(f);
    unsigned int r = (u + 0x7FFFu + ((u >> 16) & 1u)) >> 16;  // RNE
    return (ushort_t)r;
}

#define GLL16(g, l) __builtin_amdgcn_global_load_lds( \
    (const __attribute__((address_space(1))) void*)(g), \
    (__attribute__((address_space(3))) void*)(l), 16, 0, 0)

// ---------------------------------------------------------------------------
// Fused prep: x cast (blocks 0..8191), W_attn transpose (8192..8959),
// W_proj transpose (8960..9215).
// ---------------------------------------------------------------------------
__global__ __launch_bounds__(256) void prep_inputs(
    const float* __restrict__ x, ushort_t* __restrict__ xb,
    const float* __restrict__ W1, ushort_t* __restrict__ Wt1,
    const float* __restrict__ W2, ushort_t* __restrict__ Wt2)
{
    __shared__ float t[64][65];
    const int bx = blockIdx.x;
    if (bx < 8192) {
        const int i = bx * 256 + threadIdx.x;
        const float4 v = ((const float4*)x)[i];
        ushort4 o;
        o.x = f2bf(v.x); o.y = f2bf(v.y); o.z = f2bf(v.z); o.w = f2bf(v.w);
        ((ushort4*)xb)[i] = o;
        return;
    }
    const float* W; ushort_t* Wt; int N, n0, k0;
    if (bx < 8960) {
        const int tt = bx - 8192;
        W = W1; Wt = Wt1; N = C3;
        n0 = (tt % 48) * 64; k0 = (tt / 48) * 64;
    } else {
        const int tt = bx - 8960;
        W = W2; Wt = Wt2; N = C_DIM;
        n0 = (tt % 16) * 64; k0 = (tt / 16) * 64;
    }
    const int K = C_DIM;
    const int c = threadIdx.x & 63, r4 = threadIdx.x >> 6;
#pragma unroll
    for (int i = 0; i < 16; i++) {
        int r = i * 4 + r4;
        t[r][c] = W[(size_t)(k0 + r) * N + n0 + c];
    }
    __syncthreads();
#pragma unroll
    for (int i = 0; i < 16; i++) {
        int r = i * 4 + r4;
        Wt[(size_t)(n0 + r) * K + k0 + c] = f2bf(t[c][r]);
    }
}

// ---------------------------------------------------------------------------
// bf16 MFMA GEMM: 128x128 tile, BK=64, 256 threads, XOR-swizzled unpadded
// LDS staged via global_load_lds width=16. 1D grid + XCD row-clustering.
// ---------------------------------------------------------------------------
template <bool OUT_BF16, bool QSCALE>
__global__ __launch_bounds__(256, 3) void gemm_bt_mfma(
    const ushort_t* __restrict__ A, const ushort_t* __restrict__ Bt,
    const float* __restrict__ bias, void* __restrict__ Cv,
    int M, int N, int K)
{
    __shared__ ushort_t Alds[128 * 64];   // 16 KB
    __shared__ ushort_t Blds[128 * 64];   // 16 KB

    const int tid = threadIdx.x;
    const int bid = blockIdx.x;
    const int jj = bid >> 3;
    const int m0 = (((bid & 7) << 3) | (jj & 7)) * 128;   // row tile
    const int n0 = (jj >> 3) * 128;                       // col tile
    const int w = tid >> 6;
    const int ln = tid & 63;
    const int quad = ln >> 4;
    const int r16 = ln & 15;
    const int wr0 = (w & 1) * 64;
    const int wc0 = (w >> 1) * 64;

    f32x4 acc[4][4] = {};

    const int srow = tid >> 3;                       // 0..31 (row within round)
    const int csrc8 = ((tid & 7) ^ (srow & 7)) * 8;  // swizzled source elem ofs
    const int sw = r16 & 7;

    for (int k0 = 0; k0 < K; k0 += 64) {
#pragma unroll
        for (int rr = 0; rr < 4; rr++) {
            const ushort_t* ga = A + (size_t)(m0 + rr * 32 + srow) * K + k0 + csrc8;
            GLL16(ga, Alds + rr * 2048 + tid * 8);
            const ushort_t* gb = Bt + (size_t)(n0 + rr * 32 + srow) * K + k0 + csrc8;
            GLL16(gb, Blds + rr * 2048 + tid * 8);
        }
        __syncthreads();

#pragma unroll
        for (int s = 0; s < 2; s++) {
            const int cpos = ((4 * s + quad) ^ sw) * 8;
            bf16x8 af[4], bfr[4];
#pragma unroll
            for (int i = 0; i < 4; i++)
                af[i] = *(const bf16x8*)(Alds + (wr0 + i * 16 + r16) * 64 + cpos);
#pragma unroll
            for (int j = 0; j < 4; j++)
                bfr[j] = *(const bf16x8*)(Blds + (wc0 + j * 16 + r16) * 64 + cpos);
#pragma unroll
            for (int i = 0; i < 4; i++)
#pragma unroll
                for (int j = 0; j < 4; j++)
                    acc[i][j] = __builtin_amdgcn_mfma_f32_16x16x32_bf16(
                        af[i], bfr[j], acc[i][j], 0, 0, 0);
        }
        __syncthreads();
    }

    const float scl = (QSCALE && n0 < C_DIM) ? QK_SCALE : 1.0f;

#pragma unroll
    for (int j = 0; j < 4; j++) {
        const int col = n0 + wc0 + j * 16 + r16;
        const float bv = bias[col];
#pragma unroll
        for (int i = 0; i < 4; i++) {
            const int rowb = m0 + wr0 + i * 16 + quad * 4;
#pragma unroll
            for (int r = 0; r < 4; r++) {
                const float v = (acc[i][j][r] + bv) * scl;
                if (OUT_BF16)
                    ((ushort_t*)Cv)[(size_t)(rowb + r) * N + col] = f2bf(v);
                else
                    ((float*)Cv)[(size_t)(rowb + r) * N + col] = v;
            }
        }
    }
}

// ---------------------------------------------------------------------------
// V pre-transpose: qkv V-slice [b][t][2C + h*64 + d] -> vtg[bh][d][t]
// ---------------------------------------------------------------------------
__global__ __launch_bounds__(256) void transpose_v(
    const ushort_t* __restrict__ qkv, ushort_t* __restrict__ vtg)
{
    __shared__ ushort_t Ts[64][72];
    const int t0 = blockIdx.x * 64;
    const int bh = blockIdx.y;
    const int b = bh >> 4, h = bh & 15;
    const ushort_t* src = qkv + (size_t)b * T_LEN * C3 + 2 * C_DIM + h * HDIM;
    const int tid = threadIdx.x;
    {
        const int r = tid >> 2, cs = (tid & 3) * 16;
        *(u16x8*)(&Ts[r][cs])     = *(const u16x8*)(src + (size_t)(t0 + r) * C3 + cs);
        *(u16x8*)(&Ts[r][cs + 8]) = *(const u16x8*)(src + (size_t)(t0 + r) * C3 + cs + 8);
    }
    __syncthreads();
    {
        const int d = tid >> 2, ts0 = (tid & 3) * 16;
        ushort_t* dst = vtg + ((size_t)bh * HDIM + d) * T_LEN + t0 + ts0;
        u16x8 o0, o1;
#pragma unroll
        for (int j = 0; j < 8; j++) o0[j] = Ts[ts0 + j][d];
#pragma unroll
        for (int j = 0; j < 8; j++) o1[j] = Ts[ts0 + 8 + j][d];
        *(u16x8*)dst = o0;
        *(u16x8*)(dst + 8) = o1;
    }
}

// ---------------------------------------------------------------------------
// MFMA flash attention v12: v9 (known-good 69 us) + T5 s_setprio around the
// MFMA clusters. v11's depth-2 pipeline spilled accumulators to scratch
// (2.5 GB HBM traffic) -- reverted. setprio adds ZERO register liveness;
// mechanism: 4 blocks/CU at different phases (different i, independent
// barriers) -> CU scheduler prefers MFMA-entering waves over staging/VALU
// waves (m191: +4-7% on attn with independent blocks).
// ---------------------------------------------------------------------------

__device__ __forceinline__ void mask_diag(f32x4 (&s)[4], int qloc, int quad)
{
#pragma unroll
    for (int mb = 0; mb < 4; mb++)
#pragma unroll
        for (int r = 0; r < 4; r++)
            if (mb * 16 + quad * 4 + r > qloc) s[mb][r] = -1e30f;
}

// exp2 -> per-lane partial sum -> pack bf16 (RTZ) -> cross-quad permlane
// exchange -> PV B-frags. No LDS.
__device__ __forceinline__ void softmax_exchange(
    f32x4 (&s)[4], float& lacc, bf16x8 (&bp)[2])
{
    unsigned int pk[4][2];
#pragma unroll
    for (int mb = 0; mb < 4; mb++) {
        const float p0 = FAST_EXP2(s[mb][0]);
        const float p1 = FAST_EXP2(s[mb][1]);
        const float p2 = FAST_EXP2(s[mb][2]);
        const float p3 = FAST_EXP2(s[mb][3]);
        lacc += (p0 + p1) + (p2 + p3);
        pk[mb][0] = __builtin_amdgcn_perm(__float_as_uint(p1), __float_as_uint(p0), 0x07060302u);
        pk[mb][1] = __builtin_amdgcn_perm(__float_as_uint(p3), __float_as_uint(p2), 0x07060302u);
    }
#pragma unroll
    for (int s2 = 0; s2 < 2; s2++) {
        uint4 t;
#pragma unroll
        for (int u = 0; u < 2; u++) {
            unsigned int A = pk[2 * s2][u], B = pk[2 * s2 + 1][u];
            unsigned int out1, out2;
#ifdef HAVE_PERMLANE_SWAP
            u32x2 r1 = __builtin_amdgcn_permlane32_swap(A, B, false, false);
            u32x2 r2 = __builtin_amdgcn_permlane16_swap(r1.x, r1.y, false, false);
            out1 = r2.x; out2 = r2.y;
#else
            asm volatile("s_nop 1\n\t"
                         "v_permlane32_swap_b32 %0, %1\n\t"
                         "s_nop 1\n\t"
                         "v_permlane16_swap_b32 %0, %1"
                         : "+v"(A), "+v"(B));
            out1 = A; out2 = B;
#endif
            if (u == 0) { t.x = out1; t.z = out2; }
            else        { t.y = out1; t.w = out2; }
        }
        bp[s2] = *(bf16x8*)&t;
    }
}

// Issue the 2 global_load_lds for K tile [k][d] of iteration kt_ into
// double-buffer half buf_. No waits.
#define STAGE_K(kt_, buf_) do {                                               \
    const int _k0 = (kt_) * 64;                                               \
    const int _bo = (buf_) * 4096;                                            \
    _Pragma("unroll")                                                         \
    for (int rr = 0; rr < 2; rr++) {                                          \
        const ushort_t* gk = basek + (size_t)(_k0 + rr * 32 + srow) * C3 + csrc8; \
        GLL16(gk, Ks + _bo + rr * 2048 + tid * 8);                            \
    }                                                                         \
} while (0)

// Same for Vt tile [d][k].
#define STAGE_V(kt_, buf_) do {                                               \
    const int _k0 = (kt_) * 64;                                               \
    const int _bo = (buf_) * 4096;                                            \
    _Pragma("unroll")                                                         \
    for (int rr = 0; rr < 2; rr++) {                                          \
        const ushort_t* gv = vrow + (size_t)(rr * 32 + srow) * T_LEN + _k0 + csrc8; \
        GLL16(gv, Vs + _bo + rr * 2048 + tid * 8);                            \
    }                                                                         \
} while (0)

__global__ __launch_bounds__(256, 4) void attn_flash_mfma5(
    const ushort_t* __restrict__ qkv, const ushort_t* __restrict__ vtg,
    ushort_t* __restrict__ y)
{
    __shared__ ushort_t Ks[2 * 64 * 64];  // 16 KB, double-buffered, XOR swizzle
    __shared__ ushort_t Vs[2 * 64 * 64];  // 16 KB, double-buffered, Vt [d][k]

    // ---- head-clustered XCD swizzle ----
    const int bid = blockIdx.x;            // 0..1023
    const int i = (bid >> 3) >> 3;         // pair index 0..15
    const int bh = (bid & 7) * 8 + ((bid >> 3) & 7);
    const int b = bh >> 4, h = bh & 15;
    const int qA0 = i * 64;
    const int qB0 = (31 - i) * 64;
    const int lastkt = 31 - i;

    const int tid = threadIdx.x;
    const int w = tid >> 6;
    const int ln = tid & 63;
    const int quad = ln >> 4;
    const int r16 = ln & 15;
    const int qloc = w * 16 + r16;
    const int sw = r16 & 7;

    const int srow = tid >> 3;                       // 0..31
    const int csrc8 = ((tid & 7) ^ (srow & 7)) * 8;  // swizzled source chunk
    const int cpos0 = (quad ^ sw) * 8;               // s=0 read pos; s=1: ^32

    const ushort_t* baseq = qkv + (size_t)b * T_LEN * C3 + h * HDIM;
    const ushort_t* basek = baseq + C_DIM;
    const ushort_t* vrow = vtg + (size_t)bh * HDIM * T_LEN;

    // ---- stage K(0)/V(0) into buffer 0; Q frags straight from global ----
    STAGE_K(0, 0);
    STAGE_V(0, 0);

    bf16x8 aqA[2], aqB[2];
#pragma unroll
    for (int s = 0; s < 2; s++) {
        aqA[s] = *(const bf16x8*)(baseq + (size_t)(qA0 + qloc) * C3 + s * 32 + quad * 8);
        aqB[s] = *(const bf16x8*)(baseq + (size_t)(qB0 + qloc) * C3 + s * 32 + quad * 8);
    }

    f32x4 oA[4] = {}, oB[4] = {};
    float lA = 0.0f, lB = 0.0f;            // per-lane partials; reduced at end

    for (int kt = 0; kt <= lastkt; kt++) {
        // Single barrier per iteration: its implicit vmcnt(0) drains
        // K/V(kt) -- staged one full iteration ago (covered) -- and its
        // lgkmcnt(0) closes all reads of the buffer being overwritten below.
        __syncthreads();

        if (kt < lastkt) {
            STAGE_K(kt + 1, (kt + 1) & 1);
            STAGE_V(kt + 1, (kt + 1) & 1);
        }

        const int kb = (kt & 1) * 4096;

        if (kt <= i) {
            // ---- both halves active (shared ak / av frags) ----
            f32x4 sA[4] = {}, sB[4] = {};
            __builtin_amdgcn_s_setprio(1);
#pragma unroll
            for (int s = 0; s < 2; s++)
#pragma unroll
                for (int mb = 0; mb < 4; mb++) {
                    const bf16x8 ak = *(const bf16x8*)(Ks + kb + (mb * 16 + r16) * 64 + (cpos0 ^ (s * 32)));
                    sA[mb] = __builtin_amdgcn_mfma_f32_16x16x32_bf16(ak, aqA[s], sA[mb], 0, 0, 0);
                    sB[mb] = __builtin_amdgcn_mfma_f32_16x16x32_bf16(ak, aqB[s], sB[mb], 0, 0, 0);
                }
            __builtin_amdgcn_s_setprio(0);
            if (kt == i) mask_diag(sA, qloc, quad);
            bf16x8 bpA[2], bpB[2];
            softmax_exchange(sA, lA, bpA);
            softmax_exchange(sB, lB, bpB);
            __builtin_amdgcn_s_setprio(1);
#pragma unroll
            for (int s = 0; s < 2; s++)
#pragma unroll
                for (int mb = 0; mb < 4; mb++) {
                    const bf16x8 av = *(const bf16x8*)(Vs + kb + (mb * 16 + r16) * 64 + (cpos0 ^ (s * 32)));
                    oA[mb] = __builtin_amdgcn_mfma_f32_16x16x32_bf16(av, bpA[s], oA[mb], 0, 0, 0);
                    oB[mb] = __builtin_amdgcn_mfma_f32_16x16x32_bf16(av, bpB[s], oB[mb], 0, 0, 0);
                }
            __builtin_amdgcn_s_setprio(0);
        } else {
            // ---- B-half only ----
            f32x4 sB[4] = {};
            __builtin_amdgcn_s_setprio(1);
#pragma unroll
            for (int s = 0; s < 2; s++)
#pragma unroll
                for (int mb = 0; mb < 4; mb++) {
                    const bf16x8 ak = *(const bf16x8*)(Ks + kb + (mb * 16 + r16) * 64 + (cpos0 ^ (s * 32)));
                    sB[mb] = __builtin_amdgcn_mfma_f32_16x16x32_bf16(ak, aqB[s], sB[mb], 0, 0, 0);
                }
            __builtin_amdgcn_s_setprio(0);
            if (kt == lastkt) mask_diag(sB, qloc, quad);
            bf16x8 bpB[2];
            softmax_exchange(sB, lB, bpB);
            __builtin_amdgcn_s_setprio(1);
#pragma unroll
            for (int s = 0; s < 2; s++)
#pragma unroll
                for (int mb = 0; mb < 4; mb++) {
                    const bf16x8 av = *(const bf16x8*)(Vs + kb + (mb * 16 + r16) * 64 + (cpos0 ^ (s * 32)));
                    oB[mb] = __builtin_amdgcn_mfma_f32_16x16x32_bf16(av, bpB[s], oB[mb], 0, 0, 0);
                }
            __builtin_amdgcn_s_setprio(0);
        }
    }

    // ---- epilogue: reduce l across the 4 lanes sharing each q, store ----
    lA += __shfl_xor(lA, 16); lA += __shfl_xor(lA, 32);
    lB += __shfl_xor(lB, 16); lB += __shfl_xor(lB, 32);
    {
        const float invA = 1.0f / lA;
        ushort_t* yp = y + ((size_t)(b * T_LEN + qA0 + qloc)) * C_DIM + h * HDIM;
#pragma unroll
        for (int mb = 0; mb < 4; mb++) {
            ushort4 o;
            o.x = f2bf(oA[mb][0] * invA);
            o.y = f2bf(oA[mb][1] * invA);
            o.z = f2bf(oA[mb][2] * invA);
            o.w = f2bf(oA[mb][3] * invA);
            *(ushort4*)(yp + mb * 16 + quad * 4) = o;
        }
    }
    {
        const float invB = 1.0f / lB;
        ushort_t* yp = y + ((size_t)(b * T_LEN + qB0 + qloc)) * C_DIM + h * HDIM;
#pragma unroll
        for (int mb = 0; mb < 4; mb++) {
            ushort4 o;
            o.x = f2bf(oB[mb][0] * invB);
            o.y = f2bf(oB[mb][1] * invB);
            o.z = f2bf(oB[mb][2] * invB);
            o.w = f2bf(oB[mb][3] * invB);
            *(ushort4*)(yp + mb * 16 + quad * 4) = o;
        }
    }
}

// ---------------------------------------------------------------------------
extern "C" void kernel_launch(void* const* d_in, const int* in_sizes, int n_in,
                              void* d_out, int out_size, void* d_ws, size_t ws_size,
                              hipStream_t stream)
{
    const float* x      = (const float*)d_in[0];
    const float* W_attn = (const float*)d_in[1];
    const float* b_attn = (const float*)d_in[2];
    const float* W_proj = (const float*)d_in[3];
    const float* b_proj = (const float*)d_in[4];
    float* out = (float*)d_out;

    const int M = 4 * T_LEN;  // 8192
    char* ws = (char*)d_ws;
    ushort_t* qkv = (ushort_t*)ws;
    ushort_t* xb  = (ushort_t*)(ws + 50331648);
    ushort_t* Wt1 = (ushort_t*)(ws + 67108864);
    ushort_t* yb  = (ushort_t*)(ws + 73400320);
    ushort_t* Wt2 = (ushort_t*)(ws + 90177536);
    ushort_t* vtg = (ushort_t*)(ws + 92274688);

    prep_inputs<<<9216, 256, 0, stream>>>(x, xb, W_attn, Wt1, W_proj, Wt2);

    // 1) qkv = x @ W_attn + b_attn (bf16; Q pre-scaled). 1D grid, XCD-clustered.
    gemm_bt_mfma<true, true><<<dim3((M / 128) * (C3 / 128)), 256, 0, stream>>>(
        xb, Wt1, b_attn, qkv, M, C3, C_DIM);

    transpose_v<<<dim3(T_LEN / 64, 4 * NHEAD), 256, 0, stream>>>(qkv, vtg);

    // 2) causal flash attention (v12 = v9 + setprio) -> yb bf16
    attn_flash_mfma5<<<dim3(1024), 256, 0, stream>>>(qkv, vtg, yb);

    // 3) out = y @ W_proj + b_proj (f32 out). 1D grid, XCD-clustered.
    gemm_bt_mfma<false, false><<<dim3((M / 128) * (C_DIM / 128)), 256, 0, stream>>>(
        yb, Wt2, b_proj, out, M, C_DIM, C_DIM);
}

// Round 11
// 228.610 us; speedup vs baseline: 3.4623x; 1.1626x over previous
//
#include <hip/hip_runtime.h>
#include <math.h>

// Problem constants: B=4, T=2048, C=1024, NH=16, H=64
#define T_LEN 2048
#define C_DIM 1024
#define C3    3072
#define NHEAD 16
#define HDIM  64

typedef __attribute__((ext_vector_type(8))) __bf16 bf16x8;
typedef __attribute__((ext_vector_type(8))) unsigned short u16x8;
typedef __attribute__((ext_vector_type(4))) float f32x4;
typedef __attribute__((ext_vector_type(2))) unsigned int u32x2;
typedef unsigned short ushort_t;

#define QK_SCALE 0.180336878f   // 1/sqrt(64) * log2(e), folded into Q

#if defined(__has_builtin)
#if __has_builtin(__builtin_amdgcn_exp2f)
#define FAST_EXP2(x) __builtin_amdgcn_exp2f(x)
#endif
#if __has_builtin(__builtin_amdgcn_permlane32_swap) && __has_builtin(__builtin_amdgcn_permlane16_swap)
#define HAVE_PERMLANE_SWAP 1
#endif
#endif
#ifndef FAST_EXP2
#define FAST_EXP2(x) exp2f(x)
#endif

__device__ __forceinline__ ushort_t f2bf(float f) {
    unsigned int u = __float_as_uint(f);
    unsigned int r = (u + 0x7FFFu + ((u >> 16) & 1u)) >> 16;  // RNE
    return (ushort_t)r;
}

#define GLL16(g, l) __builtin_amdgcn_global_load_lds( \
    (const __attribute__((address_space(1))) void*)(g), \
    (__attribute__((address_space(3))) void*)(l), 16, 0, 0)

// ---------------------------------------------------------------------------
// Fused prep: x cast (blocks 0..8191), W_attn transpose (8192..8959),
// W_proj transpose (8960..9215).
// ---------------------------------------------------------------------------
__global__ __launch_bounds__(256) void prep_inputs(
    const float* __restrict__ x, ushort_t* __restrict__ xb,
    const float* __restrict__ W1, ushort_t* __restrict__ Wt1,
    const float* __restrict__ W2, ushort_t* __restrict__ Wt2)
{
    __shared__ float t[64][65];
    const int bx = blockIdx.x;
    if (bx < 8192) {
        const int i = bx * 256 + threadIdx.x;
        const float4 v = ((const float4*)x)[i];
        ushort4 o;
        o.x = f2bf(v.x); o.y = f2bf(v.y); o.z = f2bf(v.z); o.w = f2bf(v.w);
        ((ushort4*)xb)[i] = o;
        return;
    }
    const float* W; ushort_t* Wt; int N, n0, k0;
    if (bx < 8960) {
        const int tt = bx - 8192;
        W = W1; Wt = Wt1; N = C3;
        n0 = (tt % 48) * 64; k0 = (tt / 48) * 64;
    } else {
        const int tt = bx - 8960;
        W = W2; Wt = Wt2; N = C_DIM;
        n0 = (tt % 16) * 64; k0 = (tt / 16) * 64;
    }
    const int K = C_DIM;
    const int c = threadIdx.x & 63, r4 = threadIdx.x >> 6;
#pragma unroll
    for (int i = 0; i < 16; i++) {
        int r = i * 4 + r4;
        t[r][c] = W[(size_t)(k0 + r) * N + n0 + c];
    }
    __syncthreads();
#pragma unroll
    for (int i = 0; i < 16; i++) {
        int r = i * 4 + r4;
        Wt[(size_t)(n0 + r) * K + k0 + c] = f2bf(t[c][r]);
    }
}

// ---------------------------------------------------------------------------
// bf16 MFMA GEMM: 128x128 tile, BK=64, 256 threads, XOR-swizzled unpadded
// LDS staged via global_load_lds width=16. 1D grid + XCD row-clustering.
// ---------------------------------------------------------------------------
template <bool OUT_BF16, bool QSCALE>
__global__ __launch_bounds__(256, 3) void gemm_bt_mfma(
    const ushort_t* __restrict__ A, const ushort_t* __restrict__ Bt,
    const float* __restrict__ bias, void* __restrict__ Cv,
    int M, int N, int K)
{
    __shared__ ushort_t Alds[128 * 64];   // 16 KB
    __shared__ ushort_t Blds[128 * 64];   // 16 KB

    const int tid = threadIdx.x;
    const int bid = blockIdx.x;
    const int jj = bid >> 3;
    const int m0 = (((bid & 7) << 3) | (jj & 7)) * 128;   // row tile
    const int n0 = (jj >> 3) * 128;                       // col tile
    const int w = tid >> 6;
    const int ln = tid & 63;
    const int quad = ln >> 4;
    const int r16 = ln & 15;
    const int wr0 = (w & 1) * 64;
    const int wc0 = (w >> 1) * 64;

    f32x4 acc[4][4] = {};

    const int srow = tid >> 3;                       // 0..31 (row within round)
    const int csrc8 = ((tid & 7) ^ (srow & 7)) * 8;  // swizzled source elem ofs
    const int sw = r16 & 7;

    for (int k0 = 0; k0 < K; k0 += 64) {
#pragma unroll
        for (int rr = 0; rr < 4; rr++) {
            const ushort_t* ga = A + (size_t)(m0 + rr * 32 + srow) * K + k0 + csrc8;
            GLL16(ga, Alds + rr * 2048 + tid * 8);
            const ushort_t* gb = Bt + (size_t)(n0 + rr * 32 + srow) * K + k0 + csrc8;
            GLL16(gb, Blds + rr * 2048 + tid * 8);
        }
        __syncthreads();

#pragma unroll
        for (int s = 0; s < 2; s++) {
            const int cpos = ((4 * s + quad) ^ sw) * 8;
            bf16x8 af[4], bfr[4];
#pragma unroll
            for (int i = 0; i < 4; i++)
                af[i] = *(const bf16x8*)(Alds + (wr0 + i * 16 + r16) * 64 + cpos);
#pragma unroll
            for (int j = 0; j < 4; j++)
                bfr[j] = *(const bf16x8*)(Blds + (wc0 + j * 16 + r16) * 64 + cpos);
#pragma unroll
            for (int i = 0; i < 4; i++)
#pragma unroll
                for (int j = 0; j < 4; j++)
                    acc[i][j] = __builtin_amdgcn_mfma_f32_16x16x32_bf16(
                        af[i], bfr[j], acc[i][j], 0, 0, 0);
        }
        __syncthreads();
    }

    const float scl = (QSCALE && n0 < C_DIM) ? QK_SCALE : 1.0f;

#pragma unroll
    for (int j = 0; j < 4; j++) {
        const int col = n0 + wc0 + j * 16 + r16;
        const float bv = bias[col];
#pragma unroll
        for (int i = 0; i < 4; i++) {
            const int rowb = m0 + wr0 + i * 16 + quad * 4;
#pragma unroll
            for (int r = 0; r < 4; r++) {
                const float v = (acc[i][j][r] + bv) * scl;
                if (OUT_BF16)
                    ((ushort_t*)Cv)[(size_t)(rowb + r) * N + col] = f2bf(v);
                else
                    ((float*)Cv)[(size_t)(rowb + r) * N + col] = v;
            }
        }
    }
}

// ---------------------------------------------------------------------------
// V pre-transpose: qkv V-slice [b][t][2C + h*64 + d] -> vtg[bh][d][t]
// ---------------------------------------------------------------------------
__global__ __launch_bounds__(256) void transpose_v(
    const ushort_t* __restrict__ qkv, ushort_t* __restrict__ vtg)
{
    __shared__ ushort_t Ts[64][72];
    const int t0 = blockIdx.x * 64;
    const int bh = blockIdx.y;
    const int b = bh >> 4, h = bh & 15;
    const ushort_t* src = qkv + (size_t)b * T_LEN * C3 + 2 * C_DIM + h * HDIM;
    const int tid = threadIdx.x;
    {
        const int r = tid >> 2, cs = (tid & 3) * 16;
        *(u16x8*)(&Ts[r][cs])     = *(const u16x8*)(src + (size_t)(t0 + r) * C3 + cs);
        *(u16x8*)(&Ts[r][cs + 8]) = *(const u16x8*)(src + (size_t)(t0 + r) * C3 + cs + 8);
    }
    __syncthreads();
    {
        const int d = tid >> 2, ts0 = (tid & 3) * 16;
        ushort_t* dst = vtg + ((size_t)bh * HDIM + d) * T_LEN + t0 + ts0;
        u16x8 o0, o1;
#pragma unroll
        for (int j = 0; j < 8; j++) o0[j] = Ts[ts0 + j][d];
#pragma unroll
        for (int j = 0; j < 8; j++) o1[j] = Ts[ts0 + 8 + j][d];
        *(u16x8*)dst = o0;
        *(u16x8*)(dst + 8) = o1;
    }
}

// ---------------------------------------------------------------------------
// MFMA flash attention v13: single-q-tile blocks + backfill scheduling.
// v9's pair-block grid (1024 == residency capacity) had a ~20% tail: block
// lengths vary 17..32 iters and nothing backfills a CU whose short blocks
// finish (Occupancy 34% vs 50% full). v13: one 64-row q-tile per block
// (dual path deleted), grid 2048 > capacity (LDS 32KB -> 5 blocks/CU, 1280
// resident) so late-dispatched SHORT blocks (i = 31-ii, long first) backfill.
// Same staging, softmax_exchange, masks, epilogue as v9. No setprio (v12
// showed it starves the staging waves here).
// ---------------------------------------------------------------------------

__device__ __forceinline__ void mask_diag(f32x4 (&s)[4], int qloc, int quad)
{
#pragma unroll
    for (int mb = 0; mb < 4; mb++)
#pragma unroll
        for (int r = 0; r < 4; r++)
            if (mb * 16 + quad * 4 + r > qloc) s[mb][r] = -1e30f;
}

// exp2 -> per-lane partial sum -> pack bf16 (RTZ) -> cross-quad permlane
// exchange -> PV B-frags. No LDS.
__device__ __forceinline__ void softmax_exchange(
    f32x4 (&s)[4], float& lacc, bf16x8 (&bp)[2])
{
    unsigned int pk[4][2];
#pragma unroll
    for (int mb = 0; mb < 4; mb++) {
        const float p0 = FAST_EXP2(s[mb][0]);
        const float p1 = FAST_EXP2(s[mb][1]);
        const float p2 = FAST_EXP2(s[mb][2]);
        const float p3 = FAST_EXP2(s[mb][3]);
        lacc += (p0 + p1) + (p2 + p3);
        pk[mb][0] = __builtin_amdgcn_perm(__float_as_uint(p1), __float_as_uint(p0), 0x07060302u);
        pk[mb][1] = __builtin_amdgcn_perm(__float_as_uint(p3), __float_as_uint(p2), 0x07060302u);
    }
#pragma unroll
    for (int s2 = 0; s2 < 2; s2++) {
        uint4 t;
#pragma unroll
        for (int u = 0; u < 2; u++) {
            unsigned int A = pk[2 * s2][u], B = pk[2 * s2 + 1][u];
            unsigned int out1, out2;
#ifdef HAVE_PERMLANE_SWAP
            u32x2 r1 = __builtin_amdgcn_permlane32_swap(A, B, false, false);
            u32x2 r2 = __builtin_amdgcn_permlane16_swap(r1.x, r1.y, false, false);
            out1 = r2.x; out2 = r2.y;
#else
            asm volatile("s_nop 1\n\t"
                         "v_permlane32_swap_b32 %0, %1\n\t"
                         "s_nop 1\n\t"
                         "v_permlane16_swap_b32 %0, %1"
                         : "+v"(A), "+v"(B));
            out1 = A; out2 = B;
#endif
            if (u == 0) { t.x = out1; t.z = out2; }
            else        { t.y = out1; t.w = out2; }
        }
        bp[s2] = *(bf16x8*)&t;
    }
}

// Issue the 2 global_load_lds for K tile [k][d] of iteration kt_ into
// double-buffer half buf_. No waits.
#define STAGE_K(kt_, buf_) do {                                               \
    const int _k0 = (kt_) * 64;                                               \
    const int _bo = (buf_) * 4096;                                            \
    _Pragma("unroll")                                                         \
    for (int rr = 0; rr < 2; rr++) {                                          \
        const ushort_t* gk = basek + (size_t)(_k0 + rr * 32 + srow) * C3 + csrc8; \
        GLL16(gk, Ks + _bo + rr * 2048 + tid * 8);                            \
    }                                                                         \
} while (0)

// Same for Vt tile [d][k].
#define STAGE_V(kt_, buf_) do {                                               \
    const int _k0 = (kt_) * 64;                                               \
    const int _bo = (buf_) * 4096;                                            \
    _Pragma("unroll")                                                         \
    for (int rr = 0; rr < 2; rr++) {                                          \
        const ushort_t* gv = vrow + (size_t)(rr * 32 + srow) * T_LEN + _k0 + csrc8; \
        GLL16(gv, Vs + _bo + rr * 2048 + tid * 8);                            \
    }                                                                         \
} while (0)

__global__ __launch_bounds__(256) void attn_flash_mfma5(
    const ushort_t* __restrict__ qkv, const ushort_t* __restrict__ vtg,
    ushort_t* __restrict__ y)
{
    __shared__ ushort_t Ks[2 * 64 * 64];  // 16 KB, double-buffered, XOR swizzle
    __shared__ ushort_t Vs[2 * 64 * 64];  // 16 KB, double-buffered, Vt [d][k]

    // ---- decomposition: bid = ((ii*8 + head)*8 + xcd), long tiles first ----
    const int bid = blockIdx.x;            // 0..2047
    const int xcd = bid & 7;
    const int kk = bid >> 3;               // 0..255
    const int head = kk & 7;
    const int ii = kk >> 3;                // 0..31 (dispatch order)
    const int i = 31 - ii;                 // q-tile index: long blocks first
    const int bh = xcd * 8 + head;         // all 32 tiles of a head on one XCD
    const int b = bh >> 4, h = bh & 15;
    const int q0 = i * 64;
    const int lastkt = i;

    const int tid = threadIdx.x;
    const int w = tid >> 6;
    const int ln = tid & 63;
    const int quad = ln >> 4;
    const int r16 = ln & 15;
    const int qloc = w * 16 + r16;
    const int sw = r16 & 7;

    const int srow = tid >> 3;                       // 0..31
    const int csrc8 = ((tid & 7) ^ (srow & 7)) * 8;  // swizzled source chunk
    const int cpos0 = (quad ^ sw) * 8;               // s=0 read pos; s=1: ^32

    const ushort_t* baseq = qkv + (size_t)b * T_LEN * C3 + h * HDIM;
    const ushort_t* basek = baseq + C_DIM;
    const ushort_t* vrow = vtg + (size_t)bh * HDIM * T_LEN;

    // ---- stage K(0)/V(0) into buffer 0; Q frags straight from global ----
    STAGE_K(0, 0);
    STAGE_V(0, 0);

    bf16x8 aq[2];
#pragma unroll
    for (int s = 0; s < 2; s++)
        aq[s] = *(const bf16x8*)(baseq + (size_t)(q0 + qloc) * C3 + s * 32 + quad * 8);

    f32x4 o[4] = {};
    float l = 0.0f;                        // per-lane partial; reduced at end

    for (int kt = 0; kt <= lastkt; kt++) {
        // Single barrier per iteration: its implicit vmcnt(0) drains
        // K/V(kt) -- staged one full iteration ago (covered) -- and its
        // lgkmcnt(0) closes all reads of the buffer being overwritten below.
        __syncthreads();

        if (kt < lastkt) {
            STAGE_K(kt + 1, (kt + 1) & 1);
            STAGE_V(kt + 1, (kt + 1) & 1);
        }

        const int kb = (kt & 1) * 4096;

        f32x4 s4[4] = {};
#pragma unroll
        for (int s = 0; s < 2; s++)
#pragma unroll
            for (int mb = 0; mb < 4; mb++) {
                const bf16x8 ak = *(const bf16x8*)(Ks + kb + (mb * 16 + r16) * 64 + (cpos0 ^ (s * 32)));
                s4[mb] = __builtin_amdgcn_mfma_f32_16x16x32_bf16(ak, aq[s], s4[mb], 0, 0, 0);
            }
        if (kt == lastkt) mask_diag(s4, qloc, quad);
        bf16x8 bp[2];
        softmax_exchange(s4, l, bp);
#pragma unroll
        for (int s = 0; s < 2; s++)
#pragma unroll
            for (int mb = 0; mb < 4; mb++) {
                const bf16x8 av = *(const bf16x8*)(Vs + kb + (mb * 16 + r16) * 64 + (cpos0 ^ (s * 32)));
                o[mb] = __builtin_amdgcn_mfma_f32_16x16x32_bf16(av, bp[s], o[mb], 0, 0, 0);
            }
    }

    // ---- epilogue: reduce l across the 4 lanes sharing each q, store ----
    l += __shfl_xor(l, 16); l += __shfl_xor(l, 32);
    const float inv = 1.0f / l;
    ushort_t* yp = y + ((size_t)(b * T_LEN + q0 + qloc)) * C_DIM + h * HDIM;
#pragma unroll
    for (int mb = 0; mb < 4; mb++) {
        ushort4 ov;
        ov.x = f2bf(o[mb][0] * inv);
        ov.y = f2bf(o[mb][1] * inv);
        ov.z = f2bf(o[mb][2] * inv);
        ov.w = f2bf(o[mb][3] * inv);
        *(ushort4*)(yp + mb * 16 + quad * 4) = ov;
    }
}

// ---------------------------------------------------------------------------
extern "C" void kernel_launch(void* const* d_in, const int* in_sizes, int n_in,
                              void* d_out, int out_size, void* d_ws, size_t ws_size,
                              hipStream_t stream)
{
    const float* x      = (const float*)d_in[0];
    const float* W_attn = (const float*)d_in[1];
    const float* b_attn = (const float*)d_in[2];
    const float* W_proj = (const float*)d_in[3];
    const float* b_proj = (const float*)d_in[4];
    float* out = (float*)d_out;

    const int M = 4 * T_LEN;  // 8192
    char* ws = (char*)d_ws;
    ushort_t* qkv = (ushort_t*)ws;
    ushort_t* xb  = (ushort_t*)(ws + 50331648);
    ushort_t* Wt1 = (ushort_t*)(ws + 67108864);
    ushort_t* yb  = (ushort_t*)(ws + 73400320);
    ushort_t* Wt2 = (ushort_t*)(ws + 90177536);
    ushort_t* vtg = (ushort_t*)(ws + 92274688);

    prep_inputs<<<9216, 256, 0, stream>>>(x, xb, W_attn, Wt1, W_proj, Wt2);

    // 1) qkv = x @ W_attn + b_attn (bf16; Q pre-scaled). 1D grid, XCD-clustered.
    gemm_bt_mfma<true, true><<<dim3((M / 128) * (C3 / 128)), 256, 0, stream>>>(
        xb, Wt1, b_attn, qkv, M, C3, C_DIM);

    transpose_v<<<dim3(T_LEN / 64, 4 * NHEAD), 256, 0, stream>>>(qkv, vtg);

    // 2) causal flash attention (v13, single-tile backfill) -> yb bf16
    attn_flash_mfma5<<<dim3(2048), 256, 0, stream>>>(qkv, vtg, yb);

    // 3) out = y @ W_proj + b_proj (f32 out). 1D grid, XCD-clustered.
    gemm_bt_mfma<false, false><<<dim3((M / 128) * (C_DIM / 128)), 256, 0, stream>>>(
        yb, Wt2, b_proj, out, M, C_DIM, C_DIM);
}

// Round 12
// 224.244 us; speedup vs baseline: 3.5297x; 1.0195x over previous
//
#include <hip/hip_runtime.h>
#include <math.h>

// Problem constants: B=4, T=2048, C=1024, NH=16, H=64
#define T_LEN 2048
#define C_DIM 1024
#define C3    3072
#define NHEAD 16
#define HDIM  64

typedef __attribute__((ext_vector_type(8))) __bf16 bf16x8;
typedef __attribute__((ext_vector_type(8))) unsigned short u16x8;
typedef __attribute__((ext_vector_type(4))) float f32x4;
typedef __attribute__((ext_vector_type(2))) unsigned int u32x2;
typedef unsigned short ushort_t;

#define QK_SCALE 0.180336878f   // 1/sqrt(64) * log2(e), folded into Q

#if defined(__has_builtin)
#if __has_builtin(__builtin_amdgcn_exp2f)
#define FAST_EXP2(x) __builtin_amdgcn_exp2f(x)
#endif
#if __has_builtin(__builtin_amdgcn_permlane32_swap) && __has_builtin(__builtin_amdgcn_permlane16_swap)
#define HAVE_PERMLANE_SWAP 1
#endif
#endif
#ifndef FAST_EXP2
#define FAST_EXP2(x) exp2f(x)
#endif

__device__ __forceinline__ ushort_t f2bf(float f) {
    unsigned int u = __float_as_uint(f);
    unsigned int r = (u + 0x7FFFu + ((u >> 16) & 1u)) >> 16;  // RNE
    return (ushort_t)r;
}

#define GLL16(g, l) __builtin_amdgcn_global_load_lds( \
    (const __attribute__((address_space(1))) void*)(g), \
    (__attribute__((address_space(3))) void*)(l), 16, 0, 0)

// ---------------------------------------------------------------------------
// Fused prep: x cast (blocks 0..8191), W_attn transpose (8192..8959),
// W_proj transpose (8960..9215).
// ---------------------------------------------------------------------------
__global__ __launch_bounds__(256) void prep_inputs(
    const float* __restrict__ x, ushort_t* __restrict__ xb,
    const float* __restrict__ W1, ushort_t* __restrict__ Wt1,
    const float* __restrict__ W2, ushort_t* __restrict__ Wt2)
{
    __shared__ float t[64][65];
    const int bx = blockIdx.x;
    if (bx < 8192) {
        const int i = bx * 256 + threadIdx.x;
        const float4 v = ((const float4*)x)[i];
        ushort4 o;
        o.x = f2bf(v.x); o.y = f2bf(v.y); o.z = f2bf(v.z); o.w = f2bf(v.w);
        ((ushort4*)xb)[i] = o;
        return;
    }
    const float* W; ushort_t* Wt; int N, n0, k0;
    if (bx < 8960) {
        const int tt = bx - 8192;
        W = W1; Wt = Wt1; N = C3;
        n0 = (tt % 48) * 64; k0 = (tt / 48) * 64;
    } else {
        const int tt = bx - 8960;
        W = W2; Wt = Wt2; N = C_DIM;
        n0 = (tt % 16) * 64; k0 = (tt / 16) * 64;
    }
    const int K = C_DIM;
    const int c = threadIdx.x & 63, r4 = threadIdx.x >> 6;
#pragma unroll
    for (int i = 0; i < 16; i++) {
        int r = i * 4 + r4;
        t[r][c] = W[(size_t)(k0 + r) * N + n0 + c];
    }
    __syncthreads();
#pragma unroll
    for (int i = 0; i < 16; i++) {
        int r = i * 4 + r4;
        Wt[(size_t)(n0 + r) * K + k0 + c] = f2bf(t[c][r]);
    }
}

// ---------------------------------------------------------------------------
// bf16 MFMA GEMM: 128x128 tile, BK=64, 256 threads, XOR-swizzled unpadded
// LDS staged via global_load_lds width=16. 1D grid + XCD row-clustering.
// v14: FUSE_VT -- for GEMM1, V-region tiles (n0 >= 2C, block-uniform since
// 2048 % 128 == 0) write TRANSPOSED directly to vtg[bh][d][t] instead of
// qkv, deleting the separate transpose_v kernel (64 MB HBM round-trip).
// Per-thread the 4 r-values are consecutive t -> single ushort4 store;
// per (j,r16) the 4 quads x 4 i-blocks tile 64 consecutive t = full
// cachelines, so L2 write-combining holds.
// ---------------------------------------------------------------------------
template <bool OUT_BF16, bool QSCALE, bool FUSE_VT>
__global__ __launch_bounds__(256, 3) void gemm_bt_mfma(
    const ushort_t* __restrict__ A, const ushort_t* __restrict__ Bt,
    const float* __restrict__ bias, void* __restrict__ Cv,
    ushort_t* __restrict__ vtg,
    int M, int N, int K)
{
    __shared__ ushort_t Alds[128 * 64];   // 16 KB
    __shared__ ushort_t Blds[128 * 64];   // 16 KB

    const int tid = threadIdx.x;
    const int bid = blockIdx.x;
    const int jj = bid >> 3;
    const int m0 = (((bid & 7) << 3) | (jj & 7)) * 128;   // row tile
    const int n0 = (jj >> 3) * 128;                       // col tile
    const int w = tid >> 6;
    const int ln = tid & 63;
    const int quad = ln >> 4;
    const int r16 = ln & 15;
    const int wr0 = (w & 1) * 64;
    const int wc0 = (w >> 1) * 64;

    f32x4 acc[4][4] = {};

    const int srow = tid >> 3;                       // 0..31 (row within round)
    const int csrc8 = ((tid & 7) ^ (srow & 7)) * 8;  // swizzled source elem ofs
    const int sw = r16 & 7;

    for (int k0 = 0; k0 < K; k0 += 64) {
#pragma unroll
        for (int rr = 0; rr < 4; rr++) {
            const ushort_t* ga = A + (size_t)(m0 + rr * 32 + srow) * K + k0 + csrc8;
            GLL16(ga, Alds + rr * 2048 + tid * 8);
            const ushort_t* gb = Bt + (size_t)(n0 + rr * 32 + srow) * K + k0 + csrc8;
            GLL16(gb, Blds + rr * 2048 + tid * 8);
        }
        __syncthreads();

#pragma unroll
        for (int s = 0; s < 2; s++) {
            const int cpos = ((4 * s + quad) ^ sw) * 8;
            bf16x8 af[4], bfr[4];
#pragma unroll
            for (int i = 0; i < 4; i++)
                af[i] = *(const bf16x8*)(Alds + (wr0 + i * 16 + r16) * 64 + cpos);
#pragma unroll
            for (int j = 0; j < 4; j++)
                bfr[j] = *(const bf16x8*)(Blds + (wc0 + j * 16 + r16) * 64 + cpos);
#pragma unroll
            for (int i = 0; i < 4; i++)
#pragma unroll
                for (int j = 0; j < 4; j++)
                    acc[i][j] = __builtin_amdgcn_mfma_f32_16x16x32_bf16(
                        af[i], bfr[j], acc[i][j], 0, 0, 0);
        }
        __syncthreads();
    }

    if (FUSE_VT && n0 >= 2 * C_DIM) {
        // ---- V tile: write transposed to vtg[bh][d][t] (bias, no scale) ----
        const int bb = m0 >> 11;          // batch (uniform: 128 | 2048)
        const int t0 = m0 & 2047;
#pragma unroll
        for (int j = 0; j < 4; j++) {
            const int col = n0 + wc0 + j * 16 + r16;       // 2048..3071
            const float bv = bias[col];
            const int hd = col - 2 * C_DIM;                // h*64 + d
            ushort_t* vp = vtg + ((size_t)(bb * NHEAD * HDIM + hd)) * T_LEN;
#pragma unroll
            for (int i = 0; i < 4; i++) {
                const int tloc = t0 + wr0 + i * 16 + quad * 4;
                ushort4 o;
                o.x = f2bf(acc[i][j][0] + bv);
                o.y = f2bf(acc[i][j][1] + bv);
                o.z = f2bf(acc[i][j][2] + bv);
                o.w = f2bf(acc[i][j][3] + bv);
                *(ushort4*)(vp + tloc) = o;
            }
        }
        return;
    }

    const float scl = (QSCALE && n0 < C_DIM) ? QK_SCALE : 1.0f;

#pragma unroll
    for (int j = 0; j < 4; j++) {
        const int col = n0 + wc0 + j * 16 + r16;
        const float bv = bias[col];
#pragma unroll
        for (int i = 0; i < 4; i++) {
            const int rowb = m0 + wr0 + i * 16 + quad * 4;
#pragma unroll
            for (int r = 0; r < 4; r++) {
                const float v = (acc[i][j][r] + bv) * scl;
                if (OUT_BF16)
                    ((ushort_t*)Cv)[(size_t)(rowb + r) * N + col] = f2bf(v);
                else
                    ((float*)Cv)[(size_t)(rowb + r) * N + col] = v;
            }
        }
    }
}

// ---------------------------------------------------------------------------
// MFMA flash attention v13: single-q-tile blocks + backfill scheduling.
// One 64-row q-tile per block; grid 2048 > residency capacity (LDS 32KB ->
// 5 blocks/CU) so late-dispatched SHORT blocks (i = 31-ii, long first)
// backfill CUs as long blocks finish. K/V double-buffered via
// global_load_lds, one barrier/iter, in-register P exchange, head-clustered
// XCD swizzle.
// ---------------------------------------------------------------------------

__device__ __forceinline__ void mask_diag(f32x4 (&s)[4], int qloc, int quad)
{
#pragma unroll
    for (int mb = 0; mb < 4; mb++)
#pragma unroll
        for (int r = 0; r < 4; r++)
            if (mb * 16 + quad * 4 + r > qloc) s[mb][r] = -1e30f;
}

// exp2 -> per-lane partial sum -> pack bf16 (RTZ) -> cross-quad permlane
// exchange -> PV B-frags. No LDS.
__device__ __forceinline__ void softmax_exchange(
    f32x4 (&s)[4], float& lacc, bf16x8 (&bp)[2])
{
    unsigned int pk[4][2];
#pragma unroll
    for (int mb = 0; mb < 4; mb++) {
        const float p0 = FAST_EXP2(s[mb][0]);
        const float p1 = FAST_EXP2(s[mb][1]);
        const float p2 = FAST_EXP2(s[mb][2]);
        const float p3 = FAST_EXP2(s[mb][3]);
        lacc += (p0 + p1) + (p2 + p3);
        pk[mb][0] = __builtin_amdgcn_perm(__float_as_uint(p1), __float_as_uint(p0), 0x07060302u);
        pk[mb][1] = __builtin_amdgcn_perm(__float_as_uint(p3), __float_as_uint(p2), 0x07060302u);
    }
#pragma unroll
    for (int s2 = 0; s2 < 2; s2++) {
        uint4 t;
#pragma unroll
        for (int u = 0; u < 2; u++) {
            unsigned int A = pk[2 * s2][u], B = pk[2 * s2 + 1][u];
            unsigned int out1, out2;
#ifdef HAVE_PERMLANE_SWAP
            u32x2 r1 = __builtin_amdgcn_permlane32_swap(A, B, false, false);
            u32x2 r2 = __builtin_amdgcn_permlane16_swap(r1.x, r1.y, false, false);
            out1 = r2.x; out2 = r2.y;
#else
            asm volatile("s_nop 1\n\t"
                         "v_permlane32_swap_b32 %0, %1\n\t"
                         "s_nop 1\n\t"
                         "v_permlane16_swap_b32 %0, %1"
                         : "+v"(A), "+v"(B));
            out1 = A; out2 = B;
#endif
            if (u == 0) { t.x = out1; t.z = out2; }
            else        { t.y = out1; t.w = out2; }
        }
        bp[s2] = *(bf16x8*)&t;
    }
}

// Issue the 2 global_load_lds for K tile [k][d] of iteration kt_ into
// double-buffer half buf_. No waits.
#define STAGE_K(kt_, buf_) do {                                               \
    const int _k0 = (kt_) * 64;                                               \
    const int _bo = (buf_) * 4096;                                            \
    _Pragma("unroll")                                                         \
    for (int rr = 0; rr < 2; rr++) {                                          \
        const ushort_t* gk = basek + (size_t)(_k0 + rr * 32 + srow) * C3 + csrc8; \
        GLL16(gk, Ks + _bo + rr * 2048 + tid * 8);                            \
    }                                                                         \
} while (0)

// Same for Vt tile [d][k].
#define STAGE_V(kt_, buf_) do {                                               \
    const int _k0 = (kt_) * 64;                                               \
    const int _bo = (buf_) * 4096;                                            \
    _Pragma("unroll")                                                         \
    for (int rr = 0; rr < 2; rr++) {                                          \
        const ushort_t* gv = vrow + (size_t)(rr * 32 + srow) * T_LEN + _k0 + csrc8; \
        GLL16(gv, Vs + _bo + rr * 2048 + tid * 8);                            \
    }                                                                         \
} while (0)

__global__ __launch_bounds__(256) void attn_flash_mfma5(
    const ushort_t* __restrict__ qkv, const ushort_t* __restrict__ vtg,
    ushort_t* __restrict__ y)
{
    __shared__ ushort_t Ks[2 * 64 * 64];  // 16 KB, double-buffered, XOR swizzle
    __shared__ ushort_t Vs[2 * 64 * 64];  // 16 KB, double-buffered, Vt [d][k]

    // ---- decomposition: bid = ((ii*8 + head)*8 + xcd), long tiles first ----
    const int bid = blockIdx.x;            // 0..2047
    const int xcd = bid & 7;
    const int kk = bid >> 3;               // 0..255
    const int head = kk & 7;
    const int ii = kk >> 3;                // 0..31 (dispatch order)
    const int i = 31 - ii;                 // q-tile index: long blocks first
    const int bh = xcd * 8 + head;         // all 32 tiles of a head on one XCD
    const int b = bh >> 4, h = bh & 15;
    const int q0 = i * 64;
    const int lastkt = i;

    const int tid = threadIdx.x;
    const int w = tid >> 6;
    const int ln = tid & 63;
    const int quad = ln >> 4;
    const int r16 = ln & 15;
    const int qloc = w * 16 + r16;
    const int sw = r16 & 7;

    const int srow = tid >> 3;                       // 0..31
    const int csrc8 = ((tid & 7) ^ (srow & 7)) * 8;  // swizzled source chunk
    const int cpos0 = (quad ^ sw) * 8;               // s=0 read pos; s=1: ^32

    const ushort_t* baseq = qkv + (size_t)b * T_LEN * C3 + h * HDIM;
    const ushort_t* basek = baseq + C_DIM;
    const ushort_t* vrow = vtg + (size_t)bh * HDIM * T_LEN;

    // ---- stage K(0)/V(0) into buffer 0; Q frags straight from global ----
    STAGE_K(0, 0);
    STAGE_V(0, 0);

    bf16x8 aq[2];
#pragma unroll
    for (int s = 0; s < 2; s++)
        aq[s] = *(const bf16x8*)(baseq + (size_t)(q0 + qloc) * C3 + s * 32 + quad * 8);

    f32x4 o[4] = {};
    float l = 0.0f;                        // per-lane partial; reduced at end

    for (int kt = 0; kt <= lastkt; kt++) {
        // Single barrier per iteration: its implicit vmcnt(0) drains
        // K/V(kt) -- staged one full iteration ago (covered) -- and its
        // lgkmcnt(0) closes all reads of the buffer being overwritten below.
        __syncthreads();

        if (kt < lastkt) {
            STAGE_K(kt + 1, (kt + 1) & 1);
            STAGE_V(kt + 1, (kt + 1) & 1);
        }

        const int kb = (kt & 1) * 4096;

        f32x4 s4[4] = {};
#pragma unroll
        for (int s = 0; s < 2; s++)
#pragma unroll
            for (int mb = 0; mb < 4; mb++) {
                const bf16x8 ak = *(const bf16x8*)(Ks + kb + (mb * 16 + r16) * 64 + (cpos0 ^ (s * 32)));
                s4[mb] = __builtin_amdgcn_mfma_f32_16x16x32_bf16(ak, aq[s], s4[mb], 0, 0, 0);
            }
        if (kt == lastkt) mask_diag(s4, qloc, quad);
        bf16x8 bp[2];
        softmax_exchange(s4, l, bp);
#pragma unroll
        for (int s = 0; s < 2; s++)
#pragma unroll
            for (int mb = 0; mb < 4; mb++) {
                const bf16x8 av = *(const bf16x8*)(Vs + kb + (mb * 16 + r16) * 64 + (cpos0 ^ (s * 32)));
                o[mb] = __builtin_amdgcn_mfma_f32_16x16x32_bf16(av, bp[s], o[mb], 0, 0, 0);
            }
    }

    // ---- epilogue: reduce l across the 4 lanes sharing each q, store ----
    l += __shfl_xor(l, 16); l += __shfl_xor(l, 32);
    const float inv = 1.0f / l;
    ushort_t* yp = y + ((size_t)(b * T_LEN + q0 + qloc)) * C_DIM + h * HDIM;
#pragma unroll
    for (int mb = 0; mb < 4; mb++) {
        ushort4 ov;
        ov.x = f2bf(o[mb][0] * inv);
        ov.y = f2bf(o[mb][1] * inv);
        ov.z = f2bf(o[mb][2] * inv);
        ov.w = f2bf(o[mb][3] * inv);
        *(ushort4*)(yp + mb * 16 + quad * 4) = ov;
    }
}

// ---------------------------------------------------------------------------
extern "C" void kernel_launch(void* const* d_in, const int* in_sizes, int n_in,
                              void* d_out, int out_size, void* d_ws, size_t ws_size,
                              hipStream_t stream)
{
    const float* x      = (const float*)d_in[0];
    const float* W_attn = (const float*)d_in[1];
    const float* b_attn = (const float*)d_in[2];
    const float* W_proj = (const float*)d_in[3];
    const float* b_proj = (const float*)d_in[4];
    float* out = (float*)d_out;

    const int M = 4 * T_LEN;  // 8192
    char* ws = (char*)d_ws;
    ushort_t* qkv = (ushort_t*)ws;
    ushort_t* xb  = (ushort_t*)(ws + 50331648);
    ushort_t* Wt1 = (ushort_t*)(ws + 67108864);
    ushort_t* yb  = (ushort_t*)(ws + 73400320);
    ushort_t* Wt2 = (ushort_t*)(ws + 90177536);
    ushort_t* vtg = (ushort_t*)(ws + 92274688);

    prep_inputs<<<9216, 256, 0, stream>>>(x, xb, W_attn, Wt1, W_proj, Wt2);

    // 1) qkv = x @ W_attn + b_attn (bf16; Q pre-scaled; V written transposed
    //    straight to vtg -- transpose_v kernel deleted). 1D grid, XCD-clustered.
    gemm_bt_mfma<true, true, true><<<dim3((M / 128) * (C3 / 128)), 256, 0, stream>>>(
        xb, Wt1, b_attn, qkv, vtg, M, C3, C_DIM);

    // 2) causal flash attention (v13, single-tile backfill) -> yb bf16
    attn_flash_mfma5<<<dim3(2048), 256, 0, stream>>>(qkv, vtg, yb);

    // 3) out = y @ W_proj + b_proj (f32 out). 1D grid, XCD-clustered.
    gemm_bt_mfma<false, false, false><<<dim3((M / 128) * (C_DIM / 128)), 256, 0, stream>>>(
        yb, Wt2, b_proj, out, nullptr, M, C_DIM, C_DIM);
}